// Round 11
// baseline (988.820 us; speedup 1.0000x reference)
//
#include <hip/hip_runtime.h>
#include <hip/hip_bf16.h>
#include <math.h>

// QuantumNeuralLayer collapsed: fused = x @ Weq^T + beq, Weq = Wf @ W16r.
// R11 GEMM: R10 (32x32x16 MFMA on R8's 4-phase counted-gate schedule) with the
// R10 race fixed: cross-tile A(t+1) mb0 read moved AFTER G2's vmcnt(4)+barrier
// (which is what confirms A(t+1) landed). All other structure identical to R8.

typedef __bf16 bf16_t;
typedef __bf16 bf16x8 __attribute__((ext_vector_type(8)));
typedef __bf16 bf16x4 __attribute__((ext_vector_type(4)));
typedef float  f32x4  __attribute__((ext_vector_type(4)));
typedef float  f32x16 __attribute__((ext_vector_type(16)));

#define KC 32768
#define OD 2048
#define ID 2048
#define BSROWS 8192

#define GLL16(g, l) __builtin_amdgcn_global_load_lds( \
    (const __attribute__((address_space(1))) void*)(g), \
    (__attribute__((address_space(3))) void*)(l), 16, 0, 0)

__device__ __forceinline__ float wave_sum(float v) {
#pragma unroll
  for (int o = 32; o > 0; o >>= 1) v += __shfl_down(v, o, 64);
  return v;
}

__global__ __launch_bounds__(512, 1) void gemm256(
    const bf16_t* __restrict__ A, const bf16_t* __restrict__ B,
    float* __restrict__ C, int M, int N, int lda, int ldb,
    int Ks, int nbn, int mn)
{
  __shared__ char lds[131072];   // A: [0,65536) two 32K bufs; B: [65536,131072) four 16K slots
  const int tid  = threadIdx.x;
  const int lane = tid & 63;
  const int wave = tid >> 6;

  // T1: bijective XCD swizzle (gridDim.x % 8 == 0)
  const int nwg = gridDim.x;
  const int per = nwg >> 3;
  const int swz = (blockIdx.x & 7) * per + (blockIdx.x >> 3);
  const int z   = swz / mn;
  const int rem = swz - z * mn;
  const int bm  = (rem / nbn) * 256;
  const int bn  = (rem % nbn) * 256;
  const int k0  = z * Ks;
  float* Cz = C + (size_t)z * ((size_t)M * (size_t)N);

  const int wr = wave >> 2, wc = wave & 3;
  const int bhalf = wc >> 1;                 // which B col-half this wave consumes
  const int l31 = lane & 31;
  const int lhi = lane >> 5;                 // k-group 0/1
  const int lk7 = lane & 7;

  // swizzled 16B-slot byte offsets for k-steps 0..3 (slot = ks*2 + lhi, ^ row&7;
  // row&7 == lane&7 because all row-block offsets are multiples of 8)
  const int asl0 = (((0 * 2 + lhi)) ^ lk7) * 16;
  const int asl1 = (((1 * 2 + lhi)) ^ lk7) * 16;
  const int asl2 = (((2 * 2 + lhi)) ^ lk7) * 16;
  const int asl3 = (((3 * 2 + lhi)) ^ lk7) * 16;

  const int abase = wr * 16384 + l31 * 128;              // + mb*4096, within A buffer
  const int bloc  = ((wc & 1) * 64 + l31) * 128;         // + nb*4096, within B slot

  // stage-side: thread covers row tid>>3 (+64 per sweep); slot inverse-swizzled
  const int srow8 = tid >> 3;
  const int sw8   = (tid & 7) ^ (srow8 & 7);
  const bf16_t* gA0 = A + (size_t)(bm + srow8) * lda + k0 + sw8 * 8;
  const bf16_t* gB0 = B + (size_t)(bn + srow8) * ldb + k0 + sw8 * 8;
  const int ldw = wave * 1024;

  f32x16 acc[4][2] = {};
  bf16x8 aE[4], aO[4], bA[2][4], bB[2][4];
  const int NT = Ks >> 6;                    // K64 tiles; even, >= 4

#define STAGE_A_HALF(t, hf) do {                                          \
    _Pragma("unroll") for (int s_ = 0; s_ < 2; ++s_)                      \
      GLL16(gA0 + (size_t)((hf) * 128 + s_ * 64) * lda + (size_t)(t) * 64,\
            lds + (((t) & 1) << 15) + (hf) * 16384 + s_ * 8192 + ldw);    \
  } while (0)

#define STAGE_B_HALF(t, hh) do {                                          \
    _Pragma("unroll") for (int s_ = 0; s_ < 2; ++s_)                      \
      GLL16(gB0 + (size_t)((hh) * 128 + s_ * 64) * ldb + (size_t)(t) * 64,\
            lds + 65536 + ((((t) * 2 + (hh)) & 3) << 14) + s_ * 8192 + ldw); \
  } while (0)

  // A fragment for m-block mb: 4 b128 (one per k-step)
#define READ_A32(t, mb, ar) do {                                          \
    const char* p_ = lds + (((t) & 1) << 15) + abase + (mb) * 4096;       \
    ar[0] = *reinterpret_cast<const bf16x8*>(p_ + asl0);                  \
    ar[1] = *reinterpret_cast<const bf16x8*>(p_ + asl1);                  \
    ar[2] = *reinterpret_cast<const bf16x8*>(p_ + asl2);                  \
    ar[3] = *reinterpret_cast<const bf16x8*>(p_ + asl3);                  \
  } while (0)

  // B fragments, k-half kh (k-steps kh*2, kh*2+1) for both n-blocks: 4 b128
#define READ_B32(t, kh, bg) do {                                          \
    const char* p_ = lds + 65536 + ((((t) * 2 + bhalf) & 3) << 14) + bloc;\
    bg[0][(kh)*2]   = *reinterpret_cast<const bf16x8*>(p_ + ((kh) ? asl2 : asl0));          \
    bg[0][(kh)*2+1] = *reinterpret_cast<const bf16x8*>(p_ + ((kh) ? asl3 : asl1));          \
    bg[1][(kh)*2]   = *reinterpret_cast<const bf16x8*>(p_ + 4096 + ((kh) ? asl2 : asl0));   \
    bg[1][(kh)*2+1] = *reinterpret_cast<const bf16x8*>(p_ + 4096 + ((kh) ? asl3 : asl1));   \
  } while (0)

#define SYNCPH() do {                                                     \
    __builtin_amdgcn_s_barrier();                                         \
    asm volatile("s_waitcnt lgkmcnt(0)" ::: "memory");                    \
    __builtin_amdgcn_sched_barrier(0);                                    \
  } while (0)

  // 8 MFMA (2 n-blocks x 4 k-steps) for one m-block
#define MFMA_M(mb, ar, bg) do {                                           \
    __builtin_amdgcn_s_setprio(1);                                        \
    _Pragma("unroll") for (int ks_ = 0; ks_ < 4; ++ks_)                   \
      _Pragma("unroll") for (int nb_ = 0; nb_ < 2; ++nb_)                 \
        acc[mb][nb_] = __builtin_amdgcn_mfma_f32_32x32x16_bf16(           \
            ar[ks_], bg[nb_][ks_], acc[mb][nb_], 0, 0, 0);                \
    __builtin_amdgcn_s_setprio(0);                                        \
  } while (0)

  // TILE(t): 4 phases (one per m-block). BC = B regs for tile t; BN = shadow.
  // Cross-tile A(t+1) mb0 read happens only AFTER G2 (A(t+1) landed).
#define TILE(t, BC, BN) do {                                              \
    /* p1 */                                                              \
    if ((t) + 1 < NT) STAGE_A_HALF((t) + 1, 0);                           \
    READ_A32((t), 1, aO);                                                 \
    SYNCPH(); MFMA_M(0, aE, BC);                                          \
    /* p2 */                                                              \
    if ((t) + 1 < NT) STAGE_A_HALF((t) + 1, 1);                           \
    READ_A32((t), 2, aE);                                                 \
    SYNCPH(); MFMA_M(1, aO, BC);                                          \
    if ((t) + 1 < NT) {  /* G1: B(t+1) landed (counted) */                \
      asm volatile("s_waitcnt vmcnt(4)" ::: "memory");                    \
      __builtin_amdgcn_s_barrier();                                       \
    }                                                                     \
    /* p3 */                                                              \
    if ((t) + 2 < NT) STAGE_B_HALF((t) + 2, 0);                           \
    READ_A32((t), 3, aO);                                                 \
    if ((t) + 1 < NT) READ_B32((t) + 1, 0, BN);                           \
    SYNCPH(); MFMA_M(2, aE, BC);                                          \
    /* p4 */                                                              \
    if ((t) + 2 < NT) STAGE_B_HALF((t) + 2, 1);                           \
    if ((t) + 1 < NT) READ_B32((t) + 1, 1, BN);                           \
    SYNCPH(); MFMA_M(3, aO, BC);                                          \
    if ((t) + 2 < NT) {  /* G2: A(t+1) landed (counted) */                \
      asm volatile("s_waitcnt vmcnt(4)" ::: "memory");                    \
      __builtin_amdgcn_s_barrier();                                       \
      READ_A32((t) + 1, 0, aE);   /* safe: post-gate */                   \
    } else if ((t) + 1 < NT) {                                            \
      asm volatile("s_waitcnt vmcnt(0)" ::: "memory");  /* tail drain */  \
      __builtin_amdgcn_s_barrier();                                       \
      READ_A32((t) + 1, 0, aE);                                           \
    }                                                                     \
  } while (0)

  // prologue: stage A(0), B(0), B(1); gate A(0)+B(0); fill bA = B(0), aE = A(0) mb0
  STAGE_A_HALF(0, 0); STAGE_A_HALF(0, 1);
  STAGE_B_HALF(0, 0); STAGE_B_HALF(0, 1);
  STAGE_B_HALF(1, 0); STAGE_B_HALF(1, 1);
  asm volatile("s_waitcnt vmcnt(4)" ::: "memory");   // A(0)+B(0) landed; B(1) in flight
  __builtin_amdgcn_s_barrier();
  READ_B32(0, 0, bA);
  READ_B32(0, 1, bA);
  READ_A32(0, 0, aE);
  asm volatile("s_waitcnt lgkmcnt(0)" ::: "memory");
  __builtin_amdgcn_sched_barrier(0);
  __builtin_amdgcn_s_barrier();                      // B(0)-slot reads drained collectively

#pragma unroll 1
  for (int t = 0; t < NT; t += 2) {
    TILE(t,     bA, bB);
    TILE(t + 1, bB, bA);
  }
#undef TILE
#undef MFMA_M
#undef SYNCPH
#undef READ_B32
#undef READ_A32
#undef STAGE_B_HALF
#undef STAGE_A_HALF

  // C/D layout for 32x32x16 (m74/m101-verified):
  // col = lane&31, row = (reg&3) + 8*(reg>>2) + 4*(lane>>5)
  const int wrbase = wr * 128, wcbase = wc * 64;
#pragma unroll
  for (int mb = 0; mb < 4; ++mb)
#pragma unroll
    for (int nb = 0; nb < 2; ++nb) {
      const int col = bn + wcbase + nb * 32 + l31;
      const int row0 = bm + wrbase + mb * 32 + 4 * lhi;
#pragma unroll
      for (int g = 0; g < 4; ++g)
#pragma unroll
        for (int j = 0; j < 4; ++j)
          Cz[(size_t)(row0 + 8 * g + j) * N + col] = acc[mb][nb][g * 4 + j];
    }
}

// ---------------- Wf f32 -> bf16, and beq partial = sum_c b16[c]*Wf[o,c] ----------
__global__ void conv_wf_beq(const float* __restrict__ Wf, const float* __restrict__ b16,
                            bf16_t* __restrict__ Wf16, float* __restrict__ beq)
{
  const int o  = blockIdx.y;
  const int cb = blockIdx.x * 2048;
  const int t  = threadIdx.x;
  const size_t gbase = (size_t)o * KC + cb + t * 8;
  const float4 v0 = *(const float4*)(Wf + gbase);
  const float4 v1 = *(const float4*)(Wf + gbase + 4);
  const float4 b0 = *(const float4*)(b16 + cb + t * 8);
  const float4 b1 = *(const float4*)(b16 + cb + t * 8 + 4);
  bf16x8 r;
  r[0] = (bf16_t)v0.x; r[1] = (bf16_t)v0.y; r[2] = (bf16_t)v0.z; r[3] = (bf16_t)v0.w;
  r[4] = (bf16_t)v1.x; r[5] = (bf16_t)v1.y; r[6] = (bf16_t)v1.z; r[7] = (bf16_t)v1.w;
  *reinterpret_cast<bf16x8*>(Wf16 + gbase) = r;
  float s = v0.x * b0.x + v0.y * b0.y + v0.z * b0.z + v0.w * b0.w
          + v1.x * b1.x + v1.y * b1.y + v1.z * b1.z + v1.w * b1.w;
  s = wave_sum(s);
  __shared__ float red[4];
  if ((t & 63) == 0) red[t >> 6] = s;
  __syncthreads();
  if (t == 0) atomicAdd(beq + o, red[0] + red[1] + red[2] + red[3]);
}

// ---------------- W16 [c][i] f32 -> W16T [i][c] bf16 (vectorized writes) ----------
__global__ void transpose_w16(const float* __restrict__ W, bf16_t* __restrict__ T)
{
  __shared__ bf16_t tile[64][65];
  const int cb = blockIdx.x * 64;
  const int ib = blockIdx.y * 64;
  const int tx = threadIdx.x & 63;
  const int ty = threadIdx.x >> 6;
#pragma unroll
  for (int r = ty; r < 64; r += 4)
    tile[r][tx] = (bf16_t)W[(size_t)(cb + r) * ID + ib + tx];
  __syncthreads();
  const int orow = threadIdx.x >> 3;
  const int oc8  = (threadIdx.x & 7) * 8;
#pragma unroll
  for (int rr = 0; rr < 2; ++rr) {
    const int r = orow + rr * 32;
    bf16x8 v;
#pragma unroll
    for (int j = 0; j < 8; ++j) v[j] = tile[oc8 + j][r];
    *reinterpret_cast<bf16x8*>(T + (size_t)(ib + r) * KC + cb + oc8) = v;
  }
}

// ---------------- x f32 -> bf16 ---------------------------------------------------
__global__ void conv_x(const float* __restrict__ X, bf16_t* __restrict__ X16)
{
  const size_t i = ((size_t)blockIdx.x * 256 + threadIdx.x) * 8;
  const float4 v0 = *(const float4*)(X + i);
  const float4 v1 = *(const float4*)(X + i + 4);
  bf16x8 r;
  r[0] = (bf16_t)v0.x; r[1] = (bf16_t)v0.y; r[2] = (bf16_t)v0.z; r[3] = (bf16_t)v0.w;
  r[4] = (bf16_t)v1.x; r[5] = (bf16_t)v1.y; r[6] = (bf16_t)v1.z; r[7] = (bf16_t)v1.w;
  *reinterpret_cast<bf16x8*>(X16 + i) = r;
}

// ---------------- reduce 4 K-split slabs -> Weq bf16 ------------------------------
__global__ void reduce_weq(const float* __restrict__ slabs, bf16_t* __restrict__ Weq)
{
  const size_t MN = (size_t)OD * ID;
  const size_t i = ((size_t)blockIdx.x * 256 + threadIdx.x) * 4;
  float4 a = *(const float4*)(slabs + i);
  float4 b = *(const float4*)(slabs + MN + i);
  float4 c = *(const float4*)(slabs + 2 * MN + i);
  float4 d = *(const float4*)(slabs + 3 * MN + i);
  bf16x4 r;
  r[0] = (bf16_t)(a.x + b.x + c.x + d.x);
  r[1] = (bf16_t)(a.y + b.y + c.y + d.y);
  r[2] = (bf16_t)(a.z + b.z + c.z + d.z);
  r[3] = (bf16_t)(a.w + b.w + c.w + d.w);
  *reinterpret_cast<bf16x4*>(Weq + i) = r;
}

// ---------------- bias + LayerNorm + exact GELU -----------------------------------
__global__ __launch_bounds__(256) void ln_gelu(
    const float* __restrict__ fused, const float* __restrict__ beq,
    const float* __restrict__ bfv, const float* __restrict__ gamma,
    const float* __restrict__ beta, float* __restrict__ out)
{
  const int row = blockIdx.x;
  const int t = threadIdx.x;
  const float* fr = fused + (size_t)row * OD;
  const int c0 = t * 8;
  float v[8];
  float s = 0.f, ss = 0.f;
#pragma unroll
  for (int j = 0; j < 2; ++j) {
    float4 x  = *(const float4*)(fr  + c0 + j * 4);
    float4 bq = *(const float4*)(beq + c0 + j * 4);
    float4 bb = *(const float4*)(bfv + c0 + j * 4);
    v[j * 4 + 0] = x.x + bq.x + bb.x;
    v[j * 4 + 1] = x.y + bq.y + bb.y;
    v[j * 4 + 2] = x.z + bq.z + bb.z;
    v[j * 4 + 3] = x.w + bq.w + bb.w;
#pragma unroll
    for (int e = 0; e < 4; ++e) { float w = v[j * 4 + e]; s += w; ss += w * w; }
  }
  s = wave_sum(s); ss = wave_sum(ss);
  __shared__ float rs[4], rss[4];
  if ((t & 63) == 0) { rs[t >> 6] = s; rss[t >> 6] = ss; }
  __syncthreads();
  const float S  = rs[0] + rs[1] + rs[2] + rs[3];
  const float SS = rss[0] + rss[1] + rss[2] + rss[3];
  const float mu   = S * (1.f / OD);
  const float var  = SS * (1.f / OD) - mu * mu;
  const float rstd = rsqrtf(var + 1e-5f);
#pragma unroll
  for (int j = 0; j < 2; ++j) {
    float4 g  = *(const float4*)(gamma + c0 + j * 4);
    float4 be = *(const float4*)(beta  + c0 + j * 4);
    float4 o;
    float xn;
    xn  = (v[j * 4 + 0] - mu) * rstd * g.x + be.x; o.x = 0.5f * xn * (1.f + erff(xn * 0.70710678118f));
    xn  = (v[j * 4 + 1] - mu) * rstd * g.y + be.y; o.y = 0.5f * xn * (1.f + erff(xn * 0.70710678118f));
    xn  = (v[j * 4 + 2] - mu) * rstd * g.z + be.z; o.z = 0.5f * xn * (1.f + erff(xn * 0.70710678118f));
    xn  = (v[j * 4 + 3] - mu) * rstd * g.w + be.w; o.w = 0.5f * xn * (1.f + erff(xn * 0.70710678118f));
    *(float4*)(out + (size_t)row * OD + c0 + j * 4) = o;
  }
}

extern "C" void kernel_launch(void* const* d_in, const int* in_sizes, int n_in,
                              void* d_out, int out_size, void* d_ws, size_t ws_size,
                              hipStream_t stream) {
  const float* x     = (const float*)d_in[0];
  const float* W16   = (const float*)d_in[1];
  const float* b16   = (const float*)d_in[2];
  const float* Wf    = (const float*)d_in[3];
  const float* bfv   = (const float*)d_in[4];
  const float* gamma = (const float*)d_in[5];
  const float* beta  = (const float*)d_in[6];
  float* out = (float*)d_out;

  char* ws = (char*)d_ws;
  bf16_t* W16T  = (bf16_t*)(ws);                 // [2048][32768] bf16, 128 MiB
  bf16_t* Wf16  = (bf16_t*)(ws + 134217728);     // [2048][32768] bf16, 128 MiB
  bf16_t* X16   = (bf16_t*)(ws + 268435456);     // [8192][2048] bf16, 32 MiB
  bf16_t* Weq   = (bf16_t*)(ws + 301989888);     // [2048][2048] bf16, 8 MiB
  float*  beq   = (float*)(ws + 310378496);      // [2048] f32
  float*  slabs = (float*)(ws + 310386688);      // 4 x 16 MiB f32; reused as fused
  float*  fused = slabs;

  hipMemsetAsync(beq, 0, OD * sizeof(float), stream);

  conv_wf_beq<<<dim3(16, 2048), 256, 0, stream>>>(Wf, b16, Wf16, beq);
  transpose_w16<<<dim3(KC / 64, ID / 64), 256, 0, stream>>>(W16, W16T);
  conv_x<<<(BSROWS * ID) / (256 * 8), 256, 0, stream>>>(x, X16);

  // GEMM1: Weq = Wf16 [2048][32768] * W16T^T, K-split 4 -> slabs (grid 256)
  gemm256<<<256, 512, 0, stream>>>(Wf16, W16T, slabs, OD, ID, KC, KC, KC / 4, 8, 64);
  reduce_weq<<<(OD * ID) / (256 * 4), 256, 0, stream>>>(slabs, Weq);

  // GEMM2: fused = X16 [8192][2048] * Weq^T [2048][2048] (grid 32x8 = 256)
  gemm256<<<256, 512, 0, stream>>>(X16, Weq, fused, BSROWS, OD, ID, ID, ID, 8, 256);

  ln_gelu<<<BSROWS, 256, 0, stream>>>(fused, beq, bfv, gamma, beta, out);
}

// Round 12
// 544.121 us; speedup vs baseline: 1.8173x; 1.8173x over previous
//
#include <hip/hip_runtime.h>
#include <hip/hip_bf16.h>
#include <math.h>

// QuantumNeuralLayer collapsed: fused = x @ Weq^T + beq, Weq = Wf @ W16r.
// R12 GEMM: R8 verbatim (proven 243us GEMM1) + m201's second per-phase barrier
// after the MFMA cluster (lockstep interleave). Gates (vmcnt(4)) fold into the
// post-MFMA barrier of p2/p4 -- identical count arithmetic to R8.
// LDS: A dbuf-2 x 32 KiB, B ring-4 x 16 KiB; slot^=(row&7) swizzle both-sides
// (R8-verified: SQ_LDS_BANK_CONFLICT = 0). MFMA 16x16x32 (R11's 32x32 refuted).

typedef __bf16 bf16_t;
typedef __bf16 bf16x8 __attribute__((ext_vector_type(8)));
typedef __bf16 bf16x4 __attribute__((ext_vector_type(4)));
typedef float  f32x4  __attribute__((ext_vector_type(4)));

#define KC 32768
#define OD 2048
#define ID 2048
#define BSROWS 8192

#define GLL16(g, l) __builtin_amdgcn_global_load_lds( \
    (const __attribute__((address_space(1))) void*)(g), \
    (__attribute__((address_space(3))) void*)(l), 16, 0, 0)

__device__ __forceinline__ float wave_sum(float v) {
#pragma unroll
  for (int o = 32; o > 0; o >>= 1) v += __shfl_down(v, o, 64);
  return v;
}

__global__ __launch_bounds__(512, 1) void gemm256(
    const bf16_t* __restrict__ A, const bf16_t* __restrict__ B,
    float* __restrict__ C, int M, int N, int lda, int ldb,
    int Ks, int nbn, int mn)
{
  __shared__ char lds[131072];   // A: [0,65536) two 32K bufs; B: [65536,131072) four 16K slots
  const int tid  = threadIdx.x;
  const int lane = tid & 63;
  const int wave = tid >> 6;

  // T1: bijective XCD swizzle (gridDim.x % 8 == 0)
  const int nwg = gridDim.x;
  const int per = nwg >> 3;
  const int swz = (blockIdx.x & 7) * per + (blockIdx.x >> 3);
  const int z   = swz / mn;
  const int rem = swz - z * mn;
  const int bm  = (rem / nbn) * 256;
  const int bn  = (rem % nbn) * 256;
  const int k0  = z * Ks;
  float* Cz = C + (size_t)z * ((size_t)M * (size_t)N);

  const int wr = wave >> 2, wc = wave & 3;
  const int frow  = lane & 15;
  const int bhalf = wc >> 1;

  // read-side swizzled 16B-slot byte offsets for the two K32 halves
  const int rdsl0 = (((lane >> 4))     ^ (lane & 7)) * 16;
  const int rdsl1 = (((lane >> 4) + 4) ^ (lane & 7)) * 16;

  const int abase = wr * 16384 + frow * 128;       // within A buffer
  const int bloc  = ((wc & 1) * 64 + frow) * 128;  // within B slot

  // stage-side: thread covers row tid>>3 (+64 per sweep); slot inverse-swizzled
  const int srow8 = tid >> 3;
  const int sw8   = (tid & 7) ^ (srow8 & 7);
  const bf16_t* gA0 = A + (size_t)(bm + srow8) * lda + k0 + sw8 * 8;
  const bf16_t* gB0 = B + (size_t)(bn + srow8) * ldb + k0 + sw8 * 8;
  const int ldw = wave * 1024;

  f32x4 acc[8][4] = {};
  bf16x8 aqE[2][2], aqO[2][2], bA[4][2], bB[4][2];
  const int NT = Ks >> 6;                          // K64 tiles; even, >= 4

#define STAGE_A_HALF(t, hf) do {                                          \
    _Pragma("unroll") for (int s_ = 0; s_ < 2; ++s_)                      \
      GLL16(gA0 + (size_t)((hf) * 128 + s_ * 64) * lda + (size_t)(t) * 64,\
            lds + (((t) & 1) << 15) + (hf) * 16384 + s_ * 8192 + ldw);    \
  } while (0)

#define STAGE_B_HALF(t, hh) do {                                          \
    _Pragma("unroll") for (int s_ = 0; s_ < 2; ++s_)                      \
      GLL16(gB0 + (size_t)((hh) * 128 + s_ * 64) * ldb + (size_t)(t) * 64,\
            lds + 65536 + ((((t) * 2 + (hh)) & 3) << 14) + s_ * 8192 + ldw); \
  } while (0)

#define READ_AQ(t, q, aq) do {                                            \
    const char* p_ = lds + (((t) & 1) << 15) + abase + (q) * 4096;        \
    aq[0][0] = *reinterpret_cast<const bf16x8*>(p_ + rdsl0);              \
    aq[0][1] = *reinterpret_cast<const bf16x8*>(p_ + rdsl1);              \
    aq[1][0] = *reinterpret_cast<const bf16x8*>(p_ + 2048 + rdsl0);       \
    aq[1][1] = *reinterpret_cast<const bf16x8*>(p_ + 2048 + rdsl1);       \
  } while (0)

#define READ_BH(t, kh, bg) do {                                           \
    const char* p_ = lds + 65536 + ((((t) * 2 + bhalf) & 3) << 14) + bloc;\
    _Pragma("unroll") for (int n_ = 0; n_ < 4; ++n_)                      \
      bg[n_][kh] = *reinterpret_cast<const bf16x8*>(                      \
          p_ + n_ * 2048 + ((kh) ? rdsl1 : rdsl0));                       \
  } while (0)

  // m201 phase discipline: barrier -> lgkmcnt(0) -> MFMA -> [gate] -> barrier
#define PH_SYNC() do {                                                    \
    __builtin_amdgcn_s_barrier();                                         \
    asm volatile("s_waitcnt lgkmcnt(0)" ::: "memory");                    \
    __builtin_amdgcn_sched_barrier(0);                                    \
  } while (0)

#define PH_END() __builtin_amdgcn_s_barrier()

#define MFMA_Q(q, aq, bg) do {                                            \
    __builtin_amdgcn_s_setprio(1);                                        \
    _Pragma("unroll") for (int mh_ = 0; mh_ < 2; ++mh_)                   \
      _Pragma("unroll") for (int n_ = 0; n_ < 4; ++n_) {                  \
        acc[2*(q)+mh_][n_] = __builtin_amdgcn_mfma_f32_16x16x32_bf16(     \
            aq[mh_][0], bg[n_][0], acc[2*(q)+mh_][n_], 0, 0, 0);          \
        acc[2*(q)+mh_][n_] = __builtin_amdgcn_mfma_f32_16x16x32_bf16(     \
            aq[mh_][1], bg[n_][1], acc[2*(q)+mh_][n_], 0, 0, 0);          \
      }                                                                   \
    __builtin_amdgcn_s_setprio(0);                                        \
  } while (0)

  // TILE(t): 4 phases, 2 barriers each. BC = B regs for tile t; BN = shadow.
#define TILE(t, BC, BN) do {                                              \
    /* p1 */                                                              \
    if ((t) + 1 < NT) STAGE_A_HALF((t) + 1, 0);                           \
    READ_AQ((t), 0, aqE);                                                 \
    PH_SYNC(); MFMA_Q(0, aqE, BC);                                        \
    PH_END();                                                             \
    /* p2 */                                                              \
    if ((t) + 1 < NT) STAGE_A_HALF((t) + 1, 1);                           \
    READ_AQ((t), 1, aqO);                                                 \
    PH_SYNC(); MFMA_Q(1, aqO, BC);                                        \
    if ((t) + 1 < NT)  /* G1: B(t+1) landed (counted) */                  \
      asm volatile("s_waitcnt vmcnt(4)" ::: "memory");                    \
    PH_END();                                                             \
    /* p3 */                                                              \
    if ((t) + 2 < NT) STAGE_B_HALF((t) + 2, 0);                           \
    READ_AQ((t), 2, aqE);                                                 \
    if ((t) + 1 < NT) READ_BH((t) + 1, 0, BN);                            \
    PH_SYNC(); MFMA_Q(2, aqE, BC);                                        \
    PH_END();                                                             \
    /* p4 */                                                              \
    if ((t) + 2 < NT) STAGE_B_HALF((t) + 2, 1);                           \
    READ_AQ((t), 3, aqO);                                                 \
    if ((t) + 1 < NT) READ_BH((t) + 1, 1, BN);                            \
    PH_SYNC(); MFMA_Q(3, aqO, BC);                                        \
    if ((t) + 2 < NT)       /* G2: A(t+1) landed (counted) */             \
      asm volatile("s_waitcnt vmcnt(4)" ::: "memory");                    \
    else if ((t) + 1 < NT)  /* tail drain */                              \
      asm volatile("s_waitcnt vmcnt(0)" ::: "memory");                    \
    PH_END();                                                             \
  } while (0)

  // prologue: stage A(0), B(0), B(1); gate A(0)+B(0); fill bA = B(0)
  STAGE_A_HALF(0, 0); STAGE_A_HALF(0, 1);
  STAGE_B_HALF(0, 0); STAGE_B_HALF(0, 1);
  STAGE_B_HALF(1, 0); STAGE_B_HALF(1, 1);
  asm volatile("s_waitcnt vmcnt(4)" ::: "memory");   // A(0)+B(0) landed; B(1) in flight
  __builtin_amdgcn_s_barrier();
  READ_BH(0, 0, bA);
  READ_BH(0, 1, bA);
  asm volatile("s_waitcnt lgkmcnt(0)" ::: "memory");
  __builtin_amdgcn_sched_barrier(0);
  __builtin_amdgcn_s_barrier();                      // B(0)-slot reads drained collectively

#pragma unroll 1
  for (int t = 0; t < NT; t += 2) {
    TILE(t,     bA, bB);
    TILE(t + 1, bB, bA);
  }
#undef TILE
#undef MFMA_Q
#undef PH_END
#undef PH_SYNC
#undef READ_BH
#undef READ_AQ
#undef STAGE_B_HALF
#undef STAGE_A_HALF

  // C/D layout (m89-verified): col = lane&15, row = (lane>>4)*4 + j
  const int wrbase = wr * 128, wcbase = wc * 64;
  const int cr = (lane >> 4) * 4, cc = lane & 15;
#pragma unroll
  for (int m = 0; m < 8; ++m)
#pragma unroll
    for (int n = 0; n < 4; ++n) {
      size_t base = (size_t)(bm + wrbase + m * 16 + cr) * N + (bn + wcbase + n * 16 + cc);
#pragma unroll
      for (int j = 0; j < 4; ++j)
        Cz[base + (size_t)j * N] = acc[m][n][j];
    }
}

// ---------------- Wf f32 -> bf16, and beq partial = sum_c b16[c]*Wf[o,c] ----------
__global__ void conv_wf_beq(const float* __restrict__ Wf, const float* __restrict__ b16,
                            bf16_t* __restrict__ Wf16, float* __restrict__ beq)
{
  const int o  = blockIdx.y;
  const int cb = blockIdx.x * 2048;
  const int t  = threadIdx.x;
  const size_t gbase = (size_t)o * KC + cb + t * 8;
  const float4 v0 = *(const float4*)(Wf + gbase);
  const float4 v1 = *(const float4*)(Wf + gbase + 4);
  const float4 b0 = *(const float4*)(b16 + cb + t * 8);
  const float4 b1 = *(const float4*)(b16 + cb + t * 8 + 4);
  bf16x8 r;
  r[0] = (bf16_t)v0.x; r[1] = (bf16_t)v0.y; r[2] = (bf16_t)v0.z; r[3] = (bf16_t)v0.w;
  r[4] = (bf16_t)v1.x; r[5] = (bf16_t)v1.y; r[6] = (bf16_t)v1.z; r[7] = (bf16_t)v1.w;
  *reinterpret_cast<bf16x8*>(Wf16 + gbase) = r;
  float s = v0.x * b0.x + v0.y * b0.y + v0.z * b0.z + v0.w * b0.w
          + v1.x * b1.x + v1.y * b1.y + v1.z * b1.z + v1.w * b1.w;
  s = wave_sum(s);
  __shared__ float red[4];
  if ((t & 63) == 0) red[t >> 6] = s;
  __syncthreads();
  if (t == 0) atomicAdd(beq + o, red[0] + red[1] + red[2] + red[3]);
}

// ---------------- W16 [c][i] f32 -> W16T [i][c] bf16 (vectorized writes) ----------
__global__ void transpose_w16(const float* __restrict__ W, bf16_t* __restrict__ T)
{
  __shared__ bf16_t tile[64][65];
  const int cb = blockIdx.x * 64;
  const int ib = blockIdx.y * 64;
  const int tx = threadIdx.x & 63;
  const int ty = threadIdx.x >> 6;
#pragma unroll
  for (int r = ty; r < 64; r += 4)
    tile[r][tx] = (bf16_t)W[(size_t)(cb + r) * ID + ib + tx];
  __syncthreads();
  const int orow = threadIdx.x >> 3;
  const int oc8  = (threadIdx.x & 7) * 8;
#pragma unroll
  for (int rr = 0; rr < 2; ++rr) {
    const int r = orow + rr * 32;
    bf16x8 v;
#pragma unroll
    for (int j = 0; j < 8; ++j) v[j] = tile[oc8 + j][r];
    *reinterpret_cast<bf16x8*>(T + (size_t)(ib + r) * KC + cb + oc8) = v;
  }
}

// ---------------- x f32 -> bf16 ---------------------------------------------------
__global__ void conv_x(const float* __restrict__ X, bf16_t* __restrict__ X16)
{
  const size_t i = ((size_t)blockIdx.x * 256 + threadIdx.x) * 8;
  const float4 v0 = *(const float4*)(X + i);
  const float4 v1 = *(const float4*)(X + i + 4);
  bf16x8 r;
  r[0] = (bf16_t)v0.x; r[1] = (bf16_t)v0.y; r[2] = (bf16_t)v0.z; r[3] = (bf16_t)v0.w;
  r[4] = (bf16_t)v1.x; r[5] = (bf16_t)v1.y; r[6] = (bf16_t)v1.z; r[7] = (bf16_t)v1.w;
  *reinterpret_cast<bf16x8*>(X16 + i) = r;
}

// ---------------- reduce 4 K-split slabs -> Weq bf16 ------------------------------
__global__ void reduce_weq(const float* __restrict__ slabs, bf16_t* __restrict__ Weq)
{
  const size_t MN = (size_t)OD * ID;
  const size_t i = ((size_t)blockIdx.x * 256 + threadIdx.x) * 4;
  float4 a = *(const float4*)(slabs + i);
  float4 b = *(const float4*)(slabs + MN + i);
  float4 c = *(const float4*)(slabs + 2 * MN + i);
  float4 d = *(const float4*)(slabs + 3 * MN + i);
  bf16x4 r;
  r[0] = (bf16_t)(a.x + b.x + c.x + d.x);
  r[1] = (bf16_t)(a.y + b.y + c.y + d.y);
  r[2] = (bf16_t)(a.z + b.z + c.z + d.z);
  r[3] = (bf16_t)(a.w + b.w + c.w + d.w);
  *reinterpret_cast<bf16x4*>(Weq + i) = r;
}

// ---------------- bias + LayerNorm + exact GELU -----------------------------------
__global__ __launch_bounds__(256) void ln_gelu(
    const float* __restrict__ fused, const float* __restrict__ beq,
    const float* __restrict__ bfv, const float* __restrict__ gamma,
    const float* __restrict__ beta, float* __restrict__ out)
{
  const int row = blockIdx.x;
  const int t = threadIdx.x;
  const float* fr = fused + (size_t)row * OD;
  const int c0 = t * 8;
  float v[8];
  float s = 0.f, ss = 0.f;
#pragma unroll
  for (int j = 0; j < 2; ++j) {
    float4 x  = *(const float4*)(fr  + c0 + j * 4);
    float4 bq = *(const float4*)(beq + c0 + j * 4);
    float4 bb = *(const float4*)(bfv + c0 + j * 4);
    v[j * 4 + 0] = x.x + bq.x + bb.x;
    v[j * 4 + 1] = x.y + bq.y + bb.y;
    v[j * 4 + 2] = x.z + bq.z + bb.z;
    v[j * 4 + 3] = x.w + bq.w + bb.w;
#pragma unroll
    for (int e = 0; e < 4; ++e) { float w = v[j * 4 + e]; s += w; ss += w * w; }
  }
  s = wave_sum(s); ss = wave_sum(ss);
  __shared__ float rs[4], rss[4];
  if ((t & 63) == 0) { rs[t >> 6] = s; rss[t >> 6] = ss; }
  __syncthreads();
  const float S  = rs[0] + rs[1] + rs[2] + rs[3];
  const float SS = rss[0] + rss[1] + rss[2] + rss[3];
  const float mu   = S * (1.f / OD);
  const float var  = SS * (1.f / OD) - mu * mu;
  const float rstd = rsqrtf(var + 1e-5f);
#pragma unroll
  for (int j = 0; j < 2; ++j) {
    float4 g  = *(const float4*)(gamma + c0 + j * 4);
    float4 be = *(const float4*)(beta  + c0 + j * 4);
    float4 o;
    float xn;
    xn  = (v[j * 4 + 0] - mu) * rstd * g.x + be.x; o.x = 0.5f * xn * (1.f + erff(xn * 0.70710678118f));
    xn  = (v[j * 4 + 1] - mu) * rstd * g.y + be.y; o.y = 0.5f * xn * (1.f + erff(xn * 0.70710678118f));
    xn  = (v[j * 4 + 2] - mu) * rstd * g.z + be.z; o.z = 0.5f * xn * (1.f + erff(xn * 0.70710678118f));
    xn  = (v[j * 4 + 3] - mu) * rstd * g.w + be.w; o.w = 0.5f * xn * (1.f + erff(xn * 0.70710678118f));
    *(float4*)(out + (size_t)row * OD + c0 + j * 4) = o;
  }
}

extern "C" void kernel_launch(void* const* d_in, const int* in_sizes, int n_in,
                              void* d_out, int out_size, void* d_ws, size_t ws_size,
                              hipStream_t stream) {
  const float* x     = (const float*)d_in[0];
  const float* W16   = (const float*)d_in[1];
  const float* b16   = (const float*)d_in[2];
  const float* Wf    = (const float*)d_in[3];
  const float* bfv   = (const float*)d_in[4];
  const float* gamma = (const float*)d_in[5];
  const float* beta  = (const float*)d_in[6];
  float* out = (float*)d_out;

  char* ws = (char*)d_ws;
  bf16_t* W16T  = (bf16_t*)(ws);                 // [2048][32768] bf16, 128 MiB
  bf16_t* Wf16  = (bf16_t*)(ws + 134217728);     // [2048][32768] bf16, 128 MiB
  bf16_t* X16   = (bf16_t*)(ws + 268435456);     // [8192][2048] bf16, 32 MiB
  bf16_t* Weq   = (bf16_t*)(ws + 301989888);     // [2048][2048] bf16, 8 MiB
  float*  beq   = (float*)(ws + 310378496);      // [2048] f32
  float*  slabs = (float*)(ws + 310386688);      // 4 x 16 MiB f32; reused as fused
  float*  fused = slabs;

  hipMemsetAsync(beq, 0, OD * sizeof(float), stream);

  conv_wf_beq<<<dim3(16, 2048), 256, 0, stream>>>(Wf, b16, Wf16, beq);
  transpose_w16<<<dim3(KC / 64, ID / 64), 256, 0, stream>>>(W16, W16T);
  conv_x<<<(BSROWS * ID) / (256 * 8), 256, 0, stream>>>(x, X16);

  // GEMM1: Weq = Wf16 [2048][32768] * W16T^T, K-split 4 -> slabs (grid 256)
  gemm256<<<256, 512, 0, stream>>>(Wf16, W16T, slabs, OD, ID, KC, KC, KC / 4, 8, 64);
  reduce_weq<<<(OD * ID) / (256 * 4), 256, 0, stream>>>(slabs, Weq);

  // GEMM2: fused = X16 [8192][2048] * Weq^T [2048][2048] (grid 32x8 = 256)
  gemm256<<<256, 512, 0, stream>>>(X16, Weq, fused, BSROWS, OD, ID, ID, ID, 8, 256);

  ln_gelu<<<BSROWS, 256, 0, stream>>>(fused, beq, bfv, gamma, beta, out);
}

// Round 13
// 502.710 us; speedup vs baseline: 1.9670x; 1.0824x over previous
//
#include <hip/hip_runtime.h>
#include <hip/hip_bf16.h>
#include <math.h>

// QuantumNeuralLayer collapsed: fused = x @ Weq^T + beq, Weq = Wf @ W16r.
// R13: GEMM = R8 verbatim (verified best: 243us GEMM1 / 61us GEMM2, 0 LDS
// conflicts). Prep passes (Wf->bf16+beq, W16 transpose, x->bf16) fused into
// ONE kernel with block-range dispatch: removes 2 launch gaps + 2 GPU drains.

typedef __bf16 bf16_t;
typedef __bf16 bf16x8 __attribute__((ext_vector_type(8)));
typedef __bf16 bf16x4 __attribute__((ext_vector_type(4)));
typedef float  f32x4  __attribute__((ext_vector_type(4)));

#define KC 32768
#define OD 2048
#define ID 2048
#define BSROWS 8192

#define GLL16(g, l) __builtin_amdgcn_global_load_lds( \
    (const __attribute__((address_space(1))) void*)(g), \
    (__attribute__((address_space(3))) void*)(l), 16, 0, 0)

__device__ __forceinline__ float wave_sum(float v) {
#pragma unroll
  for (int o = 32; o > 0; o >>= 1) v += __shfl_down(v, o, 64);
  return v;
}

// ---------------------------------------------------------------------------
// R8 GEMM: 256x256 tile, 8 waves (2Mx4N), K-tile 64. LDS 128 KiB:
// A dbuf-2 x 32K, B ring-4 x 16K col-half slots. slot^=(row&7) swizzle
// both-sides. 4 phases/tile {stage 2 GLL; ds_read; barrier; lgkmcnt(0); MFMA};
// counted vmcnt(4)+barrier gates after p2 (B t+1) and p4 (A t+1).
// ---------------------------------------------------------------------------
__global__ __launch_bounds__(512, 1) void gemm256(
    const bf16_t* __restrict__ A, const bf16_t* __restrict__ B,
    float* __restrict__ C, int M, int N, int lda, int ldb,
    int Ks, int nbn, int mn)
{
  __shared__ char lds[131072];
  const int tid  = threadIdx.x;
  const int lane = tid & 63;
  const int wave = tid >> 6;

  const int nwg = gridDim.x;
  const int per = nwg >> 3;
  const int swz = (blockIdx.x & 7) * per + (blockIdx.x >> 3);
  const int z   = swz / mn;
  const int rem = swz - z * mn;
  const int bm  = (rem / nbn) * 256;
  const int bn  = (rem % nbn) * 256;
  const int k0  = z * Ks;
  float* Cz = C + (size_t)z * ((size_t)M * (size_t)N);

  const int wr = wave >> 2, wc = wave & 3;
  const int frow  = lane & 15;
  const int bhalf = wc >> 1;

  const int rdsl0 = (((lane >> 4))     ^ (lane & 7)) * 16;
  const int rdsl1 = (((lane >> 4) + 4) ^ (lane & 7)) * 16;

  const int abase = wr * 16384 + frow * 128;
  const int bloc  = ((wc & 1) * 64 + frow) * 128;

  const int srow8 = tid >> 3;
  const int sw8   = (tid & 7) ^ (srow8 & 7);
  const bf16_t* gA0 = A + (size_t)(bm + srow8) * lda + k0 + sw8 * 8;
  const bf16_t* gB0 = B + (size_t)(bn + srow8) * ldb + k0 + sw8 * 8;
  const int ldw = wave * 1024;

  f32x4 acc[8][4] = {};
  bf16x8 aqE[2][2], aqO[2][2], bA[4][2], bB[4][2];
  const int NT = Ks >> 6;

#define STAGE_A_HALF(t, hf) do {                                          \
    _Pragma("unroll") for (int s_ = 0; s_ < 2; ++s_)                      \
      GLL16(gA0 + (size_t)((hf) * 128 + s_ * 64) * lda + (size_t)(t) * 64,\
            lds + (((t) & 1) << 15) + (hf) * 16384 + s_ * 8192 + ldw);    \
  } while (0)

#define STAGE_B_HALF(t, hh) do {                                          \
    _Pragma("unroll") for (int s_ = 0; s_ < 2; ++s_)                      \
      GLL16(gB0 + (size_t)((hh) * 128 + s_ * 64) * ldb + (size_t)(t) * 64,\
            lds + 65536 + ((((t) * 2 + (hh)) & 3) << 14) + s_ * 8192 + ldw); \
  } while (0)

#define READ_AQ(t, q, aq) do {                                            \
    const char* p_ = lds + (((t) & 1) << 15) + abase + (q) * 4096;        \
    aq[0][0] = *reinterpret_cast<const bf16x8*>(p_ + rdsl0);              \
    aq[0][1] = *reinterpret_cast<const bf16x8*>(p_ + rdsl1);              \
    aq[1][0] = *reinterpret_cast<const bf16x8*>(p_ + 2048 + rdsl0);       \
    aq[1][1] = *reinterpret_cast<const bf16x8*>(p_ + 2048 + rdsl1);       \
  } while (0)

#define READ_BH(t, kh, bg) do {                                           \
    const char* p_ = lds + 65536 + ((((t) * 2 + bhalf) & 3) << 14) + bloc;\
    _Pragma("unroll") for (int n_ = 0; n_ < 4; ++n_)                      \
      bg[n_][kh] = *reinterpret_cast<const bf16x8*>(                      \
          p_ + n_ * 2048 + ((kh) ? rdsl1 : rdsl0));                       \
  } while (0)

#define SYNCPH() do {                                                     \
    __builtin_amdgcn_s_barrier();                                         \
    asm volatile("s_waitcnt lgkmcnt(0)" ::: "memory");                    \
    __builtin_amdgcn_sched_barrier(0);                                    \
  } while (0)

#define MFMA_Q(q, aq, bg) do {                                            \
    __builtin_amdgcn_s_setprio(1);                                        \
    _Pragma("unroll") for (int mh_ = 0; mh_ < 2; ++mh_)                   \
      _Pragma("unroll") for (int n_ = 0; n_ < 4; ++n_) {                  \
        acc[2*(q)+mh_][n_] = __builtin_amdgcn_mfma_f32_16x16x32_bf16(     \
            aq[mh_][0], bg[n_][0], acc[2*(q)+mh_][n_], 0, 0, 0);          \
        acc[2*(q)+mh_][n_] = __builtin_amdgcn_mfma_f32_16x16x32_bf16(     \
            aq[mh_][1], bg[n_][1], acc[2*(q)+mh_][n_], 0, 0, 0);          \
      }                                                                   \
    __builtin_amdgcn_s_setprio(0);                                        \
  } while (0)

#define TILE(t, BC, BN) do {                                              \
    /* p1 */                                                              \
    if ((t) + 1 < NT) STAGE_A_HALF((t) + 1, 0);                           \
    READ_AQ((t), 0, aqE);                                                 \
    SYNCPH(); MFMA_Q(0, aqE, BC);                                         \
    /* p2 */                                                              \
    if ((t) + 1 < NT) STAGE_A_HALF((t) + 1, 1);                           \
    READ_AQ((t), 1, aqO);                                                 \
    SYNCPH(); MFMA_Q(1, aqO, BC);                                         \
    if ((t) + 1 < NT) {  /* G1: B(t+1) landed (counted) */                \
      asm volatile("s_waitcnt vmcnt(4)" ::: "memory");                    \
      __builtin_amdgcn_s_barrier();                                       \
    }                                                                     \
    /* p3 */                                                              \
    if ((t) + 2 < NT) STAGE_B_HALF((t) + 2, 0);                           \
    READ_AQ((t), 2, aqE);                                                 \
    if ((t) + 1 < NT) READ_BH((t) + 1, 0, BN);                            \
    SYNCPH(); MFMA_Q(2, aqE, BC);                                         \
    /* p4 */                                                              \
    if ((t) + 2 < NT) STAGE_B_HALF((t) + 2, 1);                           \
    READ_AQ((t), 3, aqO);                                                 \
    if ((t) + 1 < NT) READ_BH((t) + 1, 1, BN);                            \
    SYNCPH(); MFMA_Q(3, aqO, BC);                                         \
    if ((t) + 2 < NT) {  /* G2: A(t+1) landed (counted) */                \
      asm volatile("s_waitcnt vmcnt(4)" ::: "memory");                    \
      __builtin_amdgcn_s_barrier();                                       \
    } else if ((t) + 1 < NT) {                                            \
      asm volatile("s_waitcnt vmcnt(0)" ::: "memory");  /* tail drain */  \
      __builtin_amdgcn_s_barrier();                                       \
    }                                                                     \
  } while (0)

  STAGE_A_HALF(0, 0); STAGE_A_HALF(0, 1);
  STAGE_B_HALF(0, 0); STAGE_B_HALF(0, 1);
  STAGE_B_HALF(1, 0); STAGE_B_HALF(1, 1);
  asm volatile("s_waitcnt vmcnt(4)" ::: "memory");
  __builtin_amdgcn_s_barrier();
  READ_BH(0, 0, bA);
  READ_BH(0, 1, bA);
  asm volatile("s_waitcnt lgkmcnt(0)" ::: "memory");
  __builtin_amdgcn_sched_barrier(0);
  __builtin_amdgcn_s_barrier();

#pragma unroll 1
  for (int t = 0; t < NT; t += 2) {
    TILE(t,     bA, bB);
    TILE(t + 1, bB, bA);
  }
#undef TILE
#undef MFMA_Q
#undef SYNCPH
#undef READ_BH
#undef READ_AQ
#undef STAGE_B_HALF
#undef STAGE_A_HALF

  const int wrbase = wr * 128, wcbase = wc * 64;
  const int cr = (lane >> 4) * 4, cc = lane & 15;
#pragma unroll
  for (int m = 0; m < 8; ++m)
#pragma unroll
    for (int n = 0; n < 4; ++n) {
      size_t base = (size_t)(bm + wrbase + m * 16 + cr) * N + (bn + wcbase + n * 16 + cc);
#pragma unroll
      for (int j = 0; j < 4; ++j)
        Cz[base + (size_t)j * N] = acc[m][n][j];
    }
}

// ---------------------------------------------------------------------------
// Fused prep: one launch, three block-range sections.
//   [0, 32768)        : Wf f32->bf16 + beq partial (o = b>>4, cb = (b&15)*2048)
//   [32768, 49152)    : W16 [c][i] f32 -> W16T [i][c] bf16 (64x64 tiles)
//   [49152, 57344)    : x f32 -> bf16 (2048 elems/block)
// ---------------------------------------------------------------------------
#define PREP_WF_BLOCKS   32768
#define PREP_TR_BLOCKS   16384
#define PREP_X_BLOCKS    8192
#define PREP_TOTAL       (PREP_WF_BLOCKS + PREP_TR_BLOCKS + PREP_X_BLOCKS)

__global__ __launch_bounds__(256) void prep_all(
    const float* __restrict__ Wf, const float* __restrict__ b16,
    const float* __restrict__ W16, const float* __restrict__ X,
    bf16_t* __restrict__ Wf16, bf16_t* __restrict__ W16T,
    bf16_t* __restrict__ X16, float* __restrict__ beq)
{
  __shared__ bf16_t tile[64][65];   // used by transpose section only
  const int b = blockIdx.x;
  const int t = threadIdx.x;

  if (b < PREP_WF_BLOCKS) {
    // ---- Wf convert + beq partial ----
    const int o  = b >> 4;
    const int cb = (b & 15) * 2048;
    const size_t gbase = (size_t)o * KC + cb + t * 8;
    const float4 v0 = *(const float4*)(Wf + gbase);
    const float4 v1 = *(const float4*)(Wf + gbase + 4);
    const float4 b0 = *(const float4*)(b16 + cb + t * 8);
    const float4 b1 = *(const float4*)(b16 + cb + t * 8 + 4);
    bf16x8 r;
    r[0] = (bf16_t)v0.x; r[1] = (bf16_t)v0.y; r[2] = (bf16_t)v0.z; r[3] = (bf16_t)v0.w;
    r[4] = (bf16_t)v1.x; r[5] = (bf16_t)v1.y; r[6] = (bf16_t)v1.z; r[7] = (bf16_t)v1.w;
    *reinterpret_cast<bf16x8*>(Wf16 + gbase) = r;
    float s = v0.x * b0.x + v0.y * b0.y + v0.z * b0.z + v0.w * b0.w
            + v1.x * b1.x + v1.y * b1.y + v1.z * b1.z + v1.w * b1.w;
    s = wave_sum(s);
    __shared__ float red[4];
    if ((t & 63) == 0) red[t >> 6] = s;
    __syncthreads();
    if (t == 0) atomicAdd(beq + o, red[0] + red[1] + red[2] + red[3]);
  } else if (b < PREP_WF_BLOCKS + PREP_TR_BLOCKS) {
    // ---- W16 transpose+convert ----
    const int idx = b - PREP_WF_BLOCKS;
    const int cb = (idx & 511) * 64;    // 512 c-blocks
    const int ib = (idx >> 9) * 64;     // 32 i-blocks
    const int tx = t & 63;
    const int ty = t >> 6;
#pragma unroll
    for (int r = ty; r < 64; r += 4)
      tile[r][tx] = (bf16_t)W16[(size_t)(cb + r) * ID + ib + tx];
    __syncthreads();
    const int orow = t >> 3;
    const int oc8  = (t & 7) * 8;
#pragma unroll
    for (int rr = 0; rr < 2; ++rr) {
      const int r = orow + rr * 32;
      bf16x8 v;
#pragma unroll
      for (int j = 0; j < 8; ++j) v[j] = tile[oc8 + j][r];
      *reinterpret_cast<bf16x8*>(W16T + (size_t)(ib + r) * KC + cb + oc8) = v;
    }
  } else {
    // ---- x convert ----
    const size_t i = ((size_t)(b - PREP_WF_BLOCKS - PREP_TR_BLOCKS) * 256 + t) * 8;
    const float4 v0 = *(const float4*)(X + i);
    const float4 v1 = *(const float4*)(X + i + 4);
    bf16x8 r;
    r[0] = (bf16_t)v0.x; r[1] = (bf16_t)v0.y; r[2] = (bf16_t)v0.z; r[3] = (bf16_t)v0.w;
    r[4] = (bf16_t)v1.x; r[5] = (bf16_t)v1.y; r[6] = (bf16_t)v1.z; r[7] = (bf16_t)v1.w;
    *reinterpret_cast<bf16x8*>(X16 + i) = r;
  }
}

// ---------------- reduce 4 K-split slabs -> Weq bf16 ------------------------------
__global__ void reduce_weq(const float* __restrict__ slabs, bf16_t* __restrict__ Weq)
{
  const size_t MN = (size_t)OD * ID;
  const size_t i = ((size_t)blockIdx.x * 256 + threadIdx.x) * 4;
  float4 a = *(const float4*)(slabs + i);
  float4 b = *(const float4*)(slabs + MN + i);
  float4 c = *(const float4*)(slabs + 2 * MN + i);
  float4 d = *(const float4*)(slabs + 3 * MN + i);
  bf16x4 r;
  r[0] = (bf16_t)(a.x + b.x + c.x + d.x);
  r[1] = (bf16_t)(a.y + b.y + c.y + d.y);
  r[2] = (bf16_t)(a.z + b.z + c.z + d.z);
  r[3] = (bf16_t)(a.w + b.w + c.w + d.w);
  *reinterpret_cast<bf16x4*>(Weq + i) = r;
}

// ---------------- bias + LayerNorm + exact GELU -----------------------------------
__global__ __launch_bounds__(256) void ln_gelu(
    const float* __restrict__ fused, const float* __restrict__ beq,
    const float* __restrict__ bfv, const float* __restrict__ gamma,
    const float* __restrict__ beta, float* __restrict__ out)
{
  const int row = blockIdx.x;
  const int t = threadIdx.x;
  const float* fr = fused + (size_t)row * OD;
  const int c0 = t * 8;
  float v[8];
  float s = 0.f, ss = 0.f;
#pragma unroll
  for (int j = 0; j < 2; ++j) {
    float4 x  = *(const float4*)(fr  + c0 + j * 4);
    float4 bq = *(const float4*)(beq + c0 + j * 4);
    float4 bb = *(const float4*)(bfv + c0 + j * 4);
    v[j * 4 + 0] = x.x + bq.x + bb.x;
    v[j * 4 + 1] = x.y + bq.y + bb.y;
    v[j * 4 + 2] = x.z + bq.z + bb.z;
    v[j * 4 + 3] = x.w + bq.w + bb.w;
#pragma unroll
    for (int e = 0; e < 4; ++e) { float w = v[j * 4 + e]; s += w; ss += w * w; }
  }
  s = wave_sum(s); ss = wave_sum(ss);
  __shared__ float rs[4], rss[4];
  if ((t & 63) == 0) { rs[t >> 6] = s; rss[t >> 6] = ss; }
  __syncthreads();
  const float S  = rs[0] + rs[1] + rs[2] + rs[3];
  const float SS = rss[0] + rss[1] + rss[2] + rss[3];
  const float mu   = S * (1.f / OD);
  const float var  = SS * (1.f / OD) - mu * mu;
  const float rstd = rsqrtf(var + 1e-5f);
#pragma unroll
  for (int j = 0; j < 2; ++j) {
    float4 g  = *(const float4*)(gamma + c0 + j * 4);
    float4 be = *(const float4*)(beta  + c0 + j * 4);
    float4 o;
    float xn;
    xn  = (v[j * 4 + 0] - mu) * rstd * g.x + be.x; o.x = 0.5f * xn * (1.f + erff(xn * 0.70710678118f));
    xn  = (v[j * 4 + 1] - mu) * rstd * g.y + be.y; o.y = 0.5f * xn * (1.f + erff(xn * 0.70710678118f));
    xn  = (v[j * 4 + 2] - mu) * rstd * g.z + be.z; o.z = 0.5f * xn * (1.f + erff(xn * 0.70710678118f));
    xn  = (v[j * 4 + 3] - mu) * rstd * g.w + be.w; o.w = 0.5f * xn * (1.f + erff(xn * 0.70710678118f));
    *(float4*)(out + (size_t)row * OD + c0 + j * 4) = o;
  }
}

extern "C" void kernel_launch(void* const* d_in, const int* in_sizes, int n_in,
                              void* d_out, int out_size, void* d_ws, size_t ws_size,
                              hipStream_t stream) {
  const float* x     = (const float*)d_in[0];
  const float* W16   = (const float*)d_in[1];
  const float* b16   = (const float*)d_in[2];
  const float* Wf    = (const float*)d_in[3];
  const float* bfv   = (const float*)d_in[4];
  const float* gamma = (const float*)d_in[5];
  const float* beta  = (const float*)d_in[6];
  float* out = (float*)d_out;

  char* ws = (char*)d_ws;
  bf16_t* W16T  = (bf16_t*)(ws);                 // [2048][32768] bf16, 128 MiB
  bf16_t* Wf16  = (bf16_t*)(ws + 134217728);     // [2048][32768] bf16, 128 MiB
  bf16_t* X16   = (bf16_t*)(ws + 268435456);     // [8192][2048] bf16, 32 MiB
  bf16_t* Weq   = (bf16_t*)(ws + 301989888);     // [2048][2048] bf16, 8 MiB
  float*  beq   = (float*)(ws + 310378496);      // [2048] f32
  float*  slabs = (float*)(ws + 310386688);      // 4 x 16 MiB f32; reused as fused
  float*  fused = slabs;

  hipMemsetAsync(beq, 0, OD * sizeof(float), stream);

  // fused prep: Wf convert + beq, W16 transpose, x convert -- one launch
  prep_all<<<PREP_TOTAL, 256, 0, stream>>>(Wf, b16, W16, x, Wf16, W16T, X16, beq);

  // GEMM1: Weq = Wf16 [2048][32768] * W16T^T, K-split 4 -> slabs (grid 256)
  gemm256<<<256, 512, 0, stream>>>(Wf16, W16T, slabs, OD, ID, KC, KC, KC / 4, 8, 64);
  reduce_weq<<<(OD * ID) / (256 * 4), 256, 0, stream>>>(slabs, Weq);

  // GEMM2: fused = X16 [8192][2048] * Weq^T [2048][2048] (grid 32x8 = 256)
  gemm256<<<256, 512, 0, stream>>>(X16, Weq, fused, BSROWS, OD, ID, ID, ID, 8, 256);

  ln_gelu<<<BSROWS, 256, 0, stream>>>(fused, beq, bfv, gamma, beta, out);
}